// Round 5
// baseline (214.504 us; speedup 1.0000x reference)
//
#include <hip/hip_runtime.h>
#include <hip/hip_bf16.h>

typedef __bf16 bf16x8 __attribute__((ext_vector_type(8)));
typedef float  f32x4  __attribute__((ext_vector_type(4)));
typedef short  s16x8  __attribute__((ext_vector_type(8)));
typedef unsigned short u16;

// round-to-nearest-even fp32 -> bf16 (as u16 bits)
static __device__ __forceinline__ u16 f2bf_rne(float f) {
  union { float f; unsigned u; } x; x.f = f;
  unsigned r = x.u + 0x7fffu + ((x.u >> 16) & 1u);
  return (u16)(r >> 16);
}

// split fp32 into bf16 hi (truncated) + bf16 lo (exact residual, truncated)
static __device__ __forceinline__ void splitbf(float f, short& hi, short& lo) {
  union { float f; unsigned u; } x; x.f = f;
  hi = (short)(x.u >> 16);
  union { unsigned u; float f; } h; h.u = x.u & 0xffff0000u;
  union { float f; unsigned u; } y; y.f = f - h.f;   // exact (Sterbenz)
  lo = (short)(y.u >> 16);
}

// One row per 4-wave block; identical to round 4 EXCEPT the staging
// mechanism (single-variable test): Q,K go global->REGISTER (coalesced
// dwordx4, the instruction type that hits 6.3 TB/s in copy ubenches) ->
// swizzled ds_write_b128, instead of global_load_lds. Cross-round evidence
// (r0-r4 all ~2.5-2.9 TB/s serviced regardless of duty cycle, occupancy,
// dup traffic) points at the gld_lds DMA path as the per-CU rate limiter;
// loads-to-registers are the known-fast path. Final LDS layout is
// bit-identical to round 4 (swizzle moved from global src addr to LDS dest
// addr), so mm1/softmax/mm2/stores and all numerics are unchanged.
//
// Swizzle (float-index within a 64-float h-row):
//   Q,K : lds[h*64 + (e ^ (((h>>3)&1)<<4))] = X[h][e]
//   P   : idx = d*64 + (e ^ ((d&15)<<2)), f32, overlays ldsK (dead after mm1)
__global__ __launch_bounds__(256, 4)
void attn64_kernel(const float* __restrict__ q, const float* __restrict__ k,
                   const float* __restrict__ v, float* __restrict__ out)
{
  __shared__ float ldsQ[4096];
  __shared__ float ldsK[4096];   // reused as swizzled f32 P after matmul1

  const int tid  = threadIdx.x;
  const int wid  = tid >> 6;
  const int lane = tid & 63;
  const int quad = lane >> 4;
  const int lo   = lane & 15;
  const int row  = blockIdx.x;

  const float* qrow = q + (size_t)row * 4096;
  const float* krow = k + (size_t)row * 4096;
  const float* vrow = v + (size_t)row * 4096;
  float*       orow = out + (size_t)row * 4096;

  // ---- Stage Q,K: 32 chunks of 1KB; wave w takes chunks [8w,8w+8)
  // (waves 0-1 -> Q, waves 2-3 -> K). Loads are plain coalesced dwordx4
  // (1KB contiguous per instruction); writes apply the swizzle on the LDS
  // destination. All 8 loads issued before any write (max overlap).
  {
    const int hl = lane >> 4;          // h-row within chunk
    const int e4 = (lane & 15) << 2;   // 4-float slot within row
    f32x4 r[8];
#pragma unroll
    for (int i = 0; i < 8; ++i) {
      const int c   = wid * 8 + i;     // 0..31
      const int sec = c >> 4;          // 0 = Q, 1 = K
      const int c4  = c & 15;
      const int h   = c4 * 4 + hl;
      const float* src = (sec ? krow : qrow) + h * 64 + e4;  // no swizzle
      r[i] = *(const f32x4*)src;
    }
#pragma unroll
    for (int i = 0; i < 8; ++i) {
      const int c   = wid * 8 + i;
      const int sec = c >> 4;
      const int c4  = c & 15;
      const int h   = c4 * 4 + hl;
      const int de  = e4 ^ (((h >> 3) & 1) << 4);            // swizzled dest
      *(f32x4*)((sec ? ldsK : ldsQ) + c4 * 256 + hl * 64 + de) = r[i];
    }
  }
  __syncthreads();   // Q,K resident (lgkmcnt drained by syncthreads)

  // ---- Issue V now (consumed in mm2, two barriers later): wave w needs only
  // its h-slice [16w,16w+16): A[m=h=16w+lo][k=e=quad*8+ks*32+j].
  // 4 f32x4 per lane, 16KB per BLOCK, no duplication.
  f32x4 xv[2][2];
#pragma unroll
  for (int ks = 0; ks < 2; ++ks) {
    const float* p = vrow + (wid * 16 + lo) * 64 + quad * 8 + ks * 32;
    xv[ks][0] = *(const f32x4*)p;
    xv[ks][1] = *(const f32x4*)(p + 4);
  }
  __builtin_amdgcn_sched_barrier(0);   // keep the V issue ahead of compute

  // ---- Q A-frags: A[m=d=wid*16+lo][k=h=ks*32+quad*8+j], hi/lo split.
  s16x8 qh[2], ql[2];
  {
    const int dcol = wid * 16 + lo;
#pragma unroll
    for (int ks = 0; ks < 2; ++ks)
#pragma unroll
      for (int j = 0; j < 8; ++j) {
        const int h = ks * 32 + quad * 8 + j;
        float x = ldsQ[h * 64 + (dcol ^ ((quad & 1) << 4))];
        short hh, ll; splitbf(x, hh, ll);
        qh[ks][j] = hh; ql[ks][j] = ll;
      }
  }

  // ---- Matmul 1: S[dslice][e] = sum_h Q[h][d] K[h][e].  24 MFMAs/wave.
  f32x4 acc[4];
#pragma unroll
  for (int et = 0; et < 4; ++et) acc[et] = (f32x4){0.f, 0.f, 0.f, 0.f};

#pragma unroll
  for (int et = 0; et < 4; ++et)
#pragma unroll
    for (int ks = 0; ks < 2; ++ks) {
      s16x8 kh, kl;
#pragma unroll
      for (int j = 0; j < 8; ++j) {
        const int h = ks * 32 + quad * 8 + j;
        float x = ldsK[h * 64 + ((lo + 16 * et) ^ ((quad & 1) << 4))];
        short hh, ll; splitbf(x, hh, ll);
        kh[j] = hh; kl[j] = ll;
      }
      bf16x8 ah = __builtin_bit_cast(bf16x8, qh[ks]);
      bf16x8 al = __builtin_bit_cast(bf16x8, ql[ks]);
      bf16x8 bh = __builtin_bit_cast(bf16x8, kh);
      bf16x8 bl = __builtin_bit_cast(bf16x8, kl);
      acc[et] = __builtin_amdgcn_mfma_f32_16x16x32_bf16(ah, bh, acc[et], 0, 0, 0);
      acc[et] = __builtin_amdgcn_mfma_f32_16x16x32_bf16(ah, bl, acc[et], 0, 0, 0);
      acc[et] = __builtin_amdgcn_mfma_f32_16x16x32_bf16(al, bh, acc[et], 0, 0, 0);
    }

  // ---- Softmax over e per row d. acc[et][r] = S[wid*16+quad*4+r][16et+lo];
  // each quad owns 4 rows, reduce across its 16 lanes.
#pragma unroll
  for (int r = 0; r < 4; ++r) {
    float m = fmaxf(fmaxf(acc[0][r], acc[1][r]), fmaxf(acc[2][r], acc[3][r]));
#pragma unroll
    for (int off = 1; off < 16; off <<= 1) m = fmaxf(m, __shfl_xor(m, off));
    float s = 0.f;
#pragma unroll
    for (int et = 0; et < 4; ++et) {
      float e0 = __expf(acc[et][r] - m);
      acc[et][r] = e0;
      s += e0;
    }
#pragma unroll
    for (int off = 1; off < 16; off <<= 1) s += __shfl_xor(s, off);
    float rs = 1.0f / s;
#pragma unroll
    for (int et = 0; et < 4; ++et) acc[et][r] *= rs;
  }

  __syncthreads();   // all waves done reading K -> safe to overlay P on ldsK

  // ---- P -> LDS (f32, swizzled idx = d*64 + (e ^ ((d&15)<<2))).
  float* P = ldsK;
#pragma unroll
  for (int r = 0; r < 4; ++r) {
    const int d   = wid * 16 + quad * 4 + r;
    const int swz = (d & 15) << 2;
#pragma unroll
    for (int et = 0; et < 4; ++et)
      P[d * 64 + ((lo + 16 * et) ^ swz)] = acc[et][r];
  }

  __syncthreads();   // P complete before cross-wave reads in mm2

  // ---- Convert V (loads issued two barriers ago -> long since landed).
  bf16x8 av[2];
#pragma unroll
  for (int ks = 0; ks < 2; ++ks) {
    s16x8 tv;
#pragma unroll
    for (int j = 0; j < 4; ++j) {
      tv[j]     = (short)f2bf_rne(xv[ks][0][j]);
      tv[4 + j] = (short)f2bf_rne(xv[ks][1][j]);
    }
    av[ks] = __builtin_bit_cast(bf16x8, tv);
  }

  // ---- Matmul 2: Out[h=16w..16w+16][d] = sum_e V[h][e] P[d][e].
  // B[k=e][n=d=16nt+lo] read from shared P; 8 MFMAs/wave.
  f32x4 acc2[4];
#pragma unroll
  for (int nt = 0; nt < 4; ++nt) acc2[nt] = (f32x4){0.f, 0.f, 0.f, 0.f};

#pragma unroll
  for (int ks = 0; ks < 2; ++ks) {
    const int eb = quad * 8 + ks * 32;
#pragma unroll
    for (int nt = 0; nt < 4; ++nt) {
      const int d    = nt * 16 + lo;
      const int pswz = lo << 2;           // (d&15)<<2
      f32x4 p0 = *(const f32x4*)&P[d * 64 + (eb ^ pswz)];
      f32x4 p1 = *(const f32x4*)&P[d * 64 + ((eb + 4) ^ pswz)];
      s16x8 tp;
#pragma unroll
      for (int j = 0; j < 4; ++j) {
        tp[j]     = (short)f2bf_rne(p0[j]);
        tp[4 + j] = (short)f2bf_rne(p1[j]);
      }
      bf16x8 bp = __builtin_bit_cast(bf16x8, tp);
      acc2[nt] = __builtin_amdgcn_mfma_f32_16x16x32_bf16(av[ks], bp, acc2[nt], 0, 0, 0);
    }
  }

  // ---- Store fp32: out[h*64+d], h = 16*wid+quad*4+r, d = lo+16nt.
#pragma unroll
  for (int nt = 0; nt < 4; ++nt)
#pragma unroll
    for (int r = 0; r < 4; ++r) {
      const int h = 16 * wid + quad * 4 + r;
      orow[h * 64 + lo + 16 * nt] = acc2[nt][r];
    }
}

extern "C" void kernel_launch(void* const* d_in, const int* in_sizes, int n_in,
                              void* d_out, int out_size, void* d_ws, size_t ws_size,
                              hipStream_t stream) {
  const float* q = (const float*)d_in[0];
  const float* k = (const float*)d_in[1];
  const float* v = (const float*)d_in[2];
  float* o = (float*)d_out;
  hipLaunchKernelGGL(attn64_kernel, dim3(4096), dim3(256), 0, stream, q, k, v, o);
}